// Round 1
// baseline (422.089 us; speedup 1.0000x reference)
//
#include <hip/hip_runtime.h>
#include <cstdint>
#include <cstddef>

typedef __bf16 bf16x8 __attribute__((ext_vector_type(8)));
typedef float f32x4 __attribute__((ext_vector_type(4)));
typedef const __attribute__((address_space(1))) void* gas_t;
typedef __attribute__((address_space(3))) void* las_t;

#define LOG2E 1.4426950408889634f

__device__ __forceinline__ unsigned short f2bf(float f) {
  union { float f; unsigned u; } v; v.f = f;
  unsigned r = v.u + 0x7FFFu + ((v.u >> 16) & 1u);   // round-to-nearest-even
  return (unsigned short)(r >> 16);
}
__device__ __forceinline__ float bf2f(unsigned short h) {
  union { unsigned u; float f; } v; v.u = ((unsigned)h) << 16;
  return v.f;
}
__device__ __forceinline__ void gll16(const void* g, void* l) {
  __builtin_amdgcn_global_load_lds((gas_t)g, (las_t)l, 16, 0, 0);
}

// ---------------- weight transpose + bf16 cast:  out[C][R] = bf16(in[R][C]) ----------------
__global__ __launch_bounds__(256) void transpose_cast(const float* __restrict__ in,
                                                      unsigned short* __restrict__ out,
                                                      int R, int C) {
  __shared__ float tile[32][33];
  int bx = blockIdx.x * 32, by = blockIdx.y * 32;
  int tx = threadIdx.x & 31, tg = threadIdx.x >> 5;   // tg: 0..7
  #pragma unroll
  for (int i = 0; i < 4; i++) {
    int r = tg * 4 + i;
    tile[r][tx] = in[(size_t)(by + r) * C + bx + tx];
  }
  __syncthreads();
  #pragma unroll
  for (int i = 0; i < 4; i++) {
    int r = tg * 4 + i;
    out[(size_t)(bx + r) * R + by + tx] = f2bf(tile[tx][r]);
  }
}

// ---------------- bias pack: bf16 bias[b][q][k] = adj>0 ? 0.1*edge*adj : -30000 ----------------
__global__ __launch_bounds__(256) void bias_pack(const int* __restrict__ adj,
                                                 const float* __restrict__ edge,
                                                 unsigned short* __restrict__ bp) {
  size_t i = ((size_t)blockIdx.x * 256 + threadIdx.x) * 4;
  int4 a = *(const int4*)(adj + i);
  float4 e = *(const float4*)(edge + i);
  ushort4 r;
  r.x = a.x > 0 ? f2bf(0.1f * e.x * (float)a.x) : f2bf(-30000.0f);
  r.y = a.y > 0 ? f2bf(0.1f * e.y * (float)a.y) : f2bf(-30000.0f);
  r.z = a.z > 0 ? f2bf(0.1f * e.z * (float)a.z) : f2bf(-30000.0f);
  r.w = a.w > 0 ? f2bf(0.1f * e.w * (float)a.w) : f2bf(-30000.0f);
  *(ushort4*)(bp + i) = r;
}

// ---------------- LayerNorm over D=512, one block per row, bf16 out ----------------
__global__ __launch_bounds__(256) void ln_kernel(const float* __restrict__ x,
                                                 const float* __restrict__ g,
                                                 const float* __restrict__ bt,
                                                 unsigned short* __restrict__ out) {
  int row = blockIdx.x, tid = threadIdx.x;
  const float* xr = x + (size_t)row * 512;
  float2 v = *(const float2*)(xr + tid * 2);
  float s = v.x + v.y, s2 = v.x * v.x + v.y * v.y;
  #pragma unroll
  for (int m = 1; m < 64; m <<= 1) { s += __shfl_xor(s, m, 64); s2 += __shfl_xor(s2, m, 64); }
  __shared__ float red[8];
  int w = tid >> 6;
  if ((tid & 63) == 0) { red[w * 2] = s; red[w * 2 + 1] = s2; }
  __syncthreads();
  float ts = red[0] + red[2] + red[4] + red[6];
  float ts2 = red[1] + red[3] + red[5] + red[7];
  float mu = ts * (1.0f / 512.0f);
  float rs = rsqrtf(ts2 * (1.0f / 512.0f) - mu * mu + 1e-5f);
  int c = tid * 2;
  ushort2 o;
  o.x = f2bf((v.x - mu) * rs * g[c] + bt[c]);
  o.y = f2bf((v.y - mu) * rs * g[c + 1] + bt[c + 1]);
  *(ushort2*)(out + (size_t)row * 512 + c) = o;
}

// ---------------- generic bf16 GEMM:  acc[m][n] = sum_k A[m][k] * Bt[n][k]  ----------------
// 128x128 block tile, BK=32, 4 waves each computing 64x64 (4x4 MFMA 16x16x32 tiles).
// LDS is stored in frag-order chunks: chunk (g*64+lane) = rows g*16+(lane&15), k-cols (lane>>4)*8..+8
// so frag ds_read_b128 = uniform base + lane*16B (conflict-free).
struct EpiQKV {
  unsigned short *q, *k, *v;
  const float *bq, *bk, *bv;
  __device__ void operator()(int m, int n, float val) const {
    int b = m >> 11, s = m & 2047;
    int which = n >> 9, col = n & 511;
    int h = col >> 6, d = col & 63;
    int bh = b * 8 + h;
    if (which == 0)      q[((size_t)bh * 2048 + s) * 64 + d] = f2bf(val + bq[col]);
    else if (which == 1) k[((size_t)bh * 2048 + s) * 64 + d] = f2bf(val + bk[col]);
    else                 v[((size_t)bh * 64 + d) * 2048 + s] = f2bf(val + bv[col]); // V transposed
  }
};
struct EpiOutProj {
  const float* x; const float* bo; float* x1;
  __device__ void operator()(int m, int n, float val) const {
    size_t idx = (size_t)m * 512 + n;
    x1[idx] = x[idx] + val + bo[n];
  }
};
struct EpiGelu {
  const float* b1; unsigned short* h;
  __device__ void operator()(int m, int n, float val) const {
    float t = val + b1[n];
    float gl = 0.5f * t * (1.0f + erff(t * 0.70710678118654752f));
    h[(size_t)m * 2048 + n] = f2bf(gl);
  }
};
struct EpiFinal {
  const float* x1; const float* b2; float* out;
  __device__ void operator()(int m, int n, float val) const {
    size_t idx = (size_t)m * 512 + n;
    out[idx] = x1[idx] + val + b2[n];
  }
};

template <typename Epi>
__global__ __launch_bounds__(256) void gemm_bt(const unsigned short* __restrict__ A,
                                               const unsigned short* __restrict__ Bt,
                                               int K, Epi epi) {
  __shared__ unsigned short a_lds[128 * 32];
  __shared__ unsigned short b_lds[128 * 32];
  const int tid = threadIdx.x;
  const int lane = tid & 63;
  const int w = tid >> 6;
  const int l15 = lane & 15, quad = lane >> 4;
  const int wm = w >> 1, wn = w & 1;
  const int m0 = blockIdx.y * 128, n0 = blockIdx.x * 128;

  f32x4 acc[4][4] = {};

  for (int k0 = 0; k0 < K; k0 += 32) {
    __syncthreads();
    #pragma unroll
    for (int i = 0; i < 2; i++) {
      int c = tid + i * 256;
      int g = c >> 6;
      int row = g * 16 + l15;
      int col = quad * 8;
      gll16(A + (size_t)(m0 + row) * K + k0 + col, a_lds + (size_t)(c & ~63) * 8);
      gll16(Bt + (size_t)(n0 + row) * K + k0 + col, b_lds + (size_t)(c & ~63) * 8);
    }
    __syncthreads();
    bf16x8 af[4], bfr[4];
    #pragma unroll
    for (int t = 0; t < 4; t++) {
      af[t]  = *(const bf16x8*)(a_lds + ((size_t)(wm * 4 + t) * 64 + lane) * 8);
      bfr[t] = *(const bf16x8*)(b_lds + ((size_t)(wn * 4 + t) * 64 + lane) * 8);
    }
    #pragma unroll
    for (int mt = 0; mt < 4; mt++)
      #pragma unroll
      for (int nt = 0; nt < 4; nt++)
        acc[mt][nt] = __builtin_amdgcn_mfma_f32_16x16x32_bf16(af[mt], bfr[nt], acc[mt][nt], 0, 0, 0);
  }
  #pragma unroll
  for (int mt = 0; mt < 4; mt++)
    #pragma unroll
    for (int nt = 0; nt < 4; nt++)
      #pragma unroll
      for (int r = 0; r < 4; r++)
        epi(m0 + wm * 64 + mt * 16 + quad * 4 + r, n0 + wn * 64 + nt * 16 + l15, acc[mt][nt][r]);
}

// ---------------- flash attention, one block per (b*8+h, 64-row q tile) ----------------
// Computes S^T per wave ([64 keys x 16 q]) so bias adds are ds_read_b64 and softmax
// reductions are 2 shuffles. Online softmax; P through padded LDS to A-layout; O in C-layout.
__global__ __launch_bounds__(256) void attn_kernel(const unsigned short* __restrict__ Q,
                                                   const unsigned short* __restrict__ Kb,
                                                   const unsigned short* __restrict__ VT,
                                                   const unsigned short* __restrict__ biasp,
                                                   unsigned short* __restrict__ out) {
  __shared__ unsigned short k_lds[64 * 64];
  __shared__ unsigned short v_lds[64 * 64];
  __shared__ unsigned short bias_lds[64 * 72];   // [64 q][64+8 k] padded
  __shared__ unsigned short p_lds[4][16 * 72];   // per wave [16 q][64+8 k] padded

  const int tid = threadIdx.x;
  const int lane = tid & 63, w = tid >> 6;
  const int l15 = lane & 15, quad = lane >> 4;
  const int bh = blockIdx.x, b = bh >> 3, h = bh & 7;
  const int q0 = blockIdx.y * 64;

  // Q B-operand frags for this wave's 16 q rows (q = q0 + w*16 + l15)
  const unsigned short* qrow = Q + ((size_t)bh * 2048 + q0 + w * 16 + l15) * 64;
  bf16x8 qf0 = *(const bf16x8*)(qrow + quad * 8);
  bf16x8 qf1 = *(const bf16x8*)(qrow + 32 + quad * 8);

  f32x4 o_acc[4] = {};
  float m_run = -3.0e38f, l_run = 0.0f;

  const unsigned short* kbase = Kb + (size_t)bh * 2048 * 64;
  const unsigned short* vbase = VT + (size_t)bh * 64 * 2048;
  const unsigned short* bbase = biasp + ((size_t)b * 2048 + q0) * 2048;

  for (int kt = 0; kt < 32; kt++) {
    const int kcol0 = kt * 64;
    // stage K tile and V^T tile in frag-order chunks (g = mt*2+kk / dt*2+kk)
    #pragma unroll
    for (int i = 0; i < 2; i++) {
      int c = tid + i * 256;
      int g = c >> 6;
      int mt = g >> 1, kk = g & 1;
      int rr = mt * 16 + l15;
      int cc = kk * 32 + quad * 8;
      gll16(kbase + (size_t)(kcol0 + rr) * 64 + cc, k_lds + (size_t)(c & ~63) * 8);
      gll16(vbase + (size_t)rr * 2048 + kcol0 + cc, v_lds + (size_t)(c & ~63) * 8);
    }
    // stage bias tile with padded stride (VGPR round-trip; global_load_lds can't pad)
    #pragma unroll
    for (int i = 0; i < 2; i++) {
      int r = (tid >> 3) + i * 32;
      int c8 = (tid & 7) * 8;
      uint4 dv = *(const uint4*)(bbase + (size_t)r * 2048 + kcol0 + c8);
      *(uint4*)(bias_lds + r * 72 + c8) = dv;
    }
    __syncthreads();

    // scores S^T: 4 mt tiles of [16 keys x 16 q]
    float sc[4][4];
    #pragma unroll
    for (int mt = 0; mt < 4; mt++) {
      f32x4 z = {0.0f, 0.0f, 0.0f, 0.0f};
      bf16x8 a0 = *(const bf16x8*)(k_lds + ((size_t)(mt * 2 + 0) * 64 + lane) * 8);
      bf16x8 a1 = *(const bf16x8*)(k_lds + ((size_t)(mt * 2 + 1) * 64 + lane) * 8);
      f32x4 accv = __builtin_amdgcn_mfma_f32_16x16x32_bf16(a0, qf0, z, 0, 0, 0);
      accv = __builtin_amdgcn_mfma_f32_16x16x32_bf16(a1, qf1, accv, 0, 0, 0);
      ushort4 bl = *(const ushort4*)(bias_lds + (w * 16 + l15) * 72 + mt * 16 + quad * 4);
      sc[mt][0] = (accv[0] * 0.125f + bf2f(bl.x)) * LOG2E;
      sc[mt][1] = (accv[1] * 0.125f + bf2f(bl.y)) * LOG2E;
      sc[mt][2] = (accv[2] * 0.125f + bf2f(bl.z)) * LOG2E;
      sc[mt][3] = (accv[3] * 0.125f + bf2f(bl.w)) * LOG2E;
    }

    // online softmax for q = w*16 + l15 (replicated across quads)
    float mx = -3.0e38f;
    #pragma unroll
    for (int mt = 0; mt < 4; mt++)
      #pragma unroll
      for (int r = 0; r < 4; r++) mx = fmaxf(mx, sc[mt][r]);
    mx = fmaxf(mx, __shfl_xor(mx, 16, 64));
    mx = fmaxf(mx, __shfl_xor(mx, 32, 64));
    float m_new = fmaxf(m_run, mx);
    float alpha = exp2f(m_run - m_new);
    m_run = m_new;

    float rsum = 0.0f;
    ushort4 pv[4];
    #pragma unroll
    for (int mt = 0; mt < 4; mt++) {
      float p0 = exp2f(sc[mt][0] - m_new);
      float p1 = exp2f(sc[mt][1] - m_new);
      float p2 = exp2f(sc[mt][2] - m_new);
      float p3 = exp2f(sc[mt][3] - m_new);
      rsum += (p0 + p1) + (p2 + p3);
      pv[mt].x = f2bf(p0); pv[mt].y = f2bf(p1); pv[mt].z = f2bf(p2); pv[mt].w = f2bf(p3);
    }
    rsum += __shfl_xor(rsum, 16, 64);
    rsum += __shfl_xor(rsum, 32, 64);
    l_run = l_run * alpha + rsum;

    // rescale O (rows are q-local = quad*4+r; alpha lives at lane l15=q-local)
    float al[4];
    #pragma unroll
    for (int r = 0; r < 4; r++) al[r] = __shfl(alpha, quad * 4 + r, 64);
    #pragma unroll
    for (int dt = 0; dt < 4; dt++) {
      o_acc[dt][0] *= al[0]; o_acc[dt][1] *= al[1];
      o_acc[dt][2] *= al[2]; o_acc[dt][3] *= al[3];
    }

    // P -> LDS (A-layout round trip), then PV MFMAs
    unsigned short* pw = p_lds[w];
    #pragma unroll
    for (int mt = 0; mt < 4; mt++)
      *(ushort4*)(pw + l15 * 72 + mt * 16 + quad * 4) = pv[mt];

    bf16x8 pf0 = *(const bf16x8*)(pw + l15 * 72 + quad * 8);
    bf16x8 pf1 = *(const bf16x8*)(pw + l15 * 72 + 32 + quad * 8);
    #pragma unroll
    for (int dt = 0; dt < 4; dt++) {
      bf16x8 v0 = *(const bf16x8*)(v_lds + ((size_t)(dt * 2 + 0) * 64 + lane) * 8);
      bf16x8 v1 = *(const bf16x8*)(v_lds + ((size_t)(dt * 2 + 1) * 64 + lane) * 8);
      o_acc[dt] = __builtin_amdgcn_mfma_f32_16x16x32_bf16(pf0, v0, o_acc[dt], 0, 0, 0);
      o_acc[dt] = __builtin_amdgcn_mfma_f32_16x16x32_bf16(pf1, v1, o_acc[dt], 0, 0, 0);
    }
    __syncthreads();
  }

  float li[4];
  #pragma unroll
  for (int r = 0; r < 4; r++) li[r] = 1.0f / __shfl(l_run, quad * 4 + r, 64);
  #pragma unroll
  for (int dt = 0; dt < 4; dt++)
    #pragma unroll
    for (int r = 0; r < 4; r++) {
      size_t idx = ((size_t)b * 2048 + q0 + w * 16 + quad * 4 + r) * 512 + h * 64 + dt * 16 + l15;
      out[idx] = f2bf(o_acc[dt][r] * li[r]);
    }
}

// ---------------- host launch ----------------
extern "C" void kernel_launch(void* const* d_in, const int* in_sizes, int n_in,
                              void* d_out, int out_size, void* d_ws, size_t ws_size,
                              hipStream_t stream) {
  (void)in_sizes; (void)n_in; (void)out_size; (void)ws_size;
  const float* x    = (const float*)d_in[0];
  const int*   adj  = (const int*)d_in[1];
  const float* edge = (const float*)d_in[2];
  const float* ln1g = (const float*)d_in[3];
  const float* ln1b = (const float*)d_in[4];
  const float* ln2g = (const float*)d_in[5];
  const float* ln2b = (const float*)d_in[6];
  const float* wq = (const float*)d_in[7];  const float* bq = (const float*)d_in[8];
  const float* wk = (const float*)d_in[9];  const float* bk = (const float*)d_in[10];
  const float* wv = (const float*)d_in[11]; const float* bv = (const float*)d_in[12];
  const float* wo = (const float*)d_in[13]; const float* bo = (const float*)d_in[14];
  const float* w1 = (const float*)d_in[15]; const float* b1 = (const float*)d_in[16];
  const float* w2 = (const float*)d_in[17]; const float* b2 = (const float*)d_in[18];
  float* out = (float*)d_out;

  char* ws = (char*)d_ws;
  unsigned short* qkvT = (unsigned short*)ws; ws += (size_t)1536 * 512 * 2;
  unsigned short* woT  = (unsigned short*)ws; ws += (size_t)512 * 512 * 2;
  unsigned short* w1T  = (unsigned short*)ws; ws += (size_t)2048 * 512 * 2;
  unsigned short* w2T  = (unsigned short*)ws; ws += (size_t)512 * 2048 * 2;
  unsigned short* bp   = (unsigned short*)ws; ws += (size_t)2 * 2048 * 2048 * 2;
  unsigned short* nx   = (unsigned short*)ws; ws += (size_t)4096 * 512 * 2;
  unsigned short* qb   = (unsigned short*)ws; ws += (size_t)16 * 2048 * 64 * 2;
  unsigned short* kb   = (unsigned short*)ws; ws += (size_t)16 * 2048 * 64 * 2;
  unsigned short* vb   = (unsigned short*)ws; ws += (size_t)16 * 64 * 2048 * 2;
  unsigned short* ao   = (unsigned short*)ws; ws += (size_t)4096 * 512 * 2;
  float*          x1   = (float*)ws;          ws += (size_t)4096 * 512 * 4;
  unsigned short* n2   = (unsigned short*)ws; ws += (size_t)4096 * 512 * 2;
  unsigned short* hb   = (unsigned short*)ws; ws += (size_t)4096 * 2048 * 2;

  dim3 blk(256);
  transpose_cast<<<dim3(16, 16), blk, 0, stream>>>(wq, qkvT, 512, 512);
  transpose_cast<<<dim3(16, 16), blk, 0, stream>>>(wk, qkvT + (size_t)512 * 512, 512, 512);
  transpose_cast<<<dim3(16, 16), blk, 0, stream>>>(wv, qkvT + (size_t)2 * 512 * 512, 512, 512);
  transpose_cast<<<dim3(16, 16), blk, 0, stream>>>(wo, woT, 512, 512);
  transpose_cast<<<dim3(64, 16), blk, 0, stream>>>(w1, w1T, 512, 2048);
  transpose_cast<<<dim3(16, 64), blk, 0, stream>>>(w2, w2T, 2048, 512);
  bias_pack<<<8192, blk, 0, stream>>>(adj, edge, bp);
  ln_kernel<<<4096, blk, 0, stream>>>(x, ln1g, ln1b, nx);
  gemm_bt<<<dim3(12, 32), blk, 0, stream>>>(nx, qkvT, 512, EpiQKV{qb, kb, vb, bq, bk, bv});
  attn_kernel<<<dim3(16, 32), blk, 0, stream>>>(qb, kb, vb, bp, ao);
  gemm_bt<<<dim3(4, 32), blk, 0, stream>>>(ao, woT, 512, EpiOutProj{x, bo, x1});
  ln_kernel<<<4096, blk, 0, stream>>>(x1, ln2g, ln2b, n2);
  gemm_bt<<<dim3(16, 32), blk, 0, stream>>>(n2, w1T, 512, EpiGelu{b1, hb});
  gemm_bt<<<dim3(4, 32), blk, 0, stream>>>(hb, w2T, 2048, EpiFinal{x1, b2, out});
}

// Round 2
// 357.002 us; speedup vs baseline: 1.1823x; 1.1823x over previous
//
#include <hip/hip_runtime.h>
#include <cstdint>
#include <cstddef>

typedef __bf16 bf16x8 __attribute__((ext_vector_type(8)));
typedef float f32x4 __attribute__((ext_vector_type(4)));
typedef const __attribute__((address_space(1))) void* gas_t;
typedef __attribute__((address_space(3))) void* las_t;

#define LOG2E 1.4426950408889634f
#define QSCALE 0.18033688011112042f   /* 0.125 * log2(e) */
#define BSCALE 0.14426950408889634f   /* 0.1 * log2(e)   */

__device__ __forceinline__ unsigned short f2bf(float f) {
  union { float f; unsigned u; } v; v.f = f;
  unsigned r = v.u + 0x7FFFu + ((v.u >> 16) & 1u);   // RNE
  return (unsigned short)(r >> 16);
}
__device__ __forceinline__ unsigned short f2bf_fast(float f) {
  union { float f; unsigned u; } v; v.f = f;
  return (unsigned short)((v.u + 0x8000u) >> 16);    // round-nearest-away (p>=0)
}
__device__ __forceinline__ float bf2f(unsigned short h) {
  union { unsigned u; float f; } v; v.u = ((unsigned)h) << 16;
  return v.f;
}
__device__ __forceinline__ void gll16(const void* g, void* l) {
  __builtin_amdgcn_global_load_lds((gas_t)g, (las_t)l, 16, 0, 0);
}

// ---------------- weight transpose + bf16 cast:  out[C][R] = bf16(in[R][C]) ----------------
__global__ __launch_bounds__(256) void transpose_cast(const float* __restrict__ in,
                                                      unsigned short* __restrict__ out,
                                                      int R, int C) {
  __shared__ float tile[32][33];
  int bx = blockIdx.x * 32, by = blockIdx.y * 32;
  int tx = threadIdx.x & 31, tg = threadIdx.x >> 5;
  #pragma unroll
  for (int i = 0; i < 4; i++) {
    int r = tg * 4 + i;
    tile[r][tx] = in[(size_t)(by + r) * C + bx + tx];
  }
  __syncthreads();
  #pragma unroll
  for (int i = 0; i < 4; i++) {
    int r = tg * 4 + i;
    out[(size_t)(bx + r) * R + by + tx] = f2bf(tile[tx][r]);
  }
}

struct TP4 { const float* in[4]; unsigned short* out[4]; };
__global__ __launch_bounds__(256) void transpose_cast4(TP4 p) {  // 512x512 each
  __shared__ float tile[32][33];
  const float* in = p.in[blockIdx.z];
  unsigned short* out = p.out[blockIdx.z];
  int bx = blockIdx.x * 32, by = blockIdx.y * 32;
  int tx = threadIdx.x & 31, tg = threadIdx.x >> 5;
  #pragma unroll
  for (int i = 0; i < 4; i++) {
    int r = tg * 4 + i;
    tile[r][tx] = in[(size_t)(by + r) * 512 + bx + tx];
  }
  __syncthreads();
  #pragma unroll
  for (int i = 0; i < 4; i++) {
    int r = tg * 4 + i;
    out[(size_t)(bx + r) * 512 + by + tx] = f2bf(tile[tx][r]);
  }
}

// ---------------- bias pack: bf16( adj>0 ? 0.1*edge*adj*log2e - 20 : -30000 ) ----------------
__global__ __launch_bounds__(256) void bias_pack(const int* __restrict__ adj,
                                                 const float* __restrict__ edge,
                                                 unsigned short* __restrict__ bp) {
  size_t i = ((size_t)blockIdx.x * 256 + threadIdx.x) * 4;
  int4 a = *(const int4*)(adj + i);
  float4 e = *(const float4*)(edge + i);
  ushort4 r;
  r.x = a.x > 0 ? f2bf(BSCALE * e.x * (float)a.x - 20.0f) : f2bf(-30000.0f);
  r.y = a.y > 0 ? f2bf(BSCALE * e.y * (float)a.y - 20.0f) : f2bf(-30000.0f);
  r.z = a.z > 0 ? f2bf(BSCALE * e.z * (float)a.z - 20.0f) : f2bf(-30000.0f);
  r.w = a.w > 0 ? f2bf(BSCALE * e.w * (float)a.w - 20.0f) : f2bf(-30000.0f);
  *(ushort4*)(bp + i) = r;
}

// ---------------- LayerNorm over D=512 (optionally fuses oinit = x + badd) ----------------
__global__ __launch_bounds__(256) void ln_kernel(const float* __restrict__ x,
                                                 const float* __restrict__ g,
                                                 const float* __restrict__ bt,
                                                 unsigned short* __restrict__ out,
                                                 const float* __restrict__ badd,
                                                 float* __restrict__ oinit) {
  int row = blockIdx.x, tid = threadIdx.x;
  const float* xr = x + (size_t)row * 512;
  float2 v = *(const float2*)(xr + tid * 2);
  float s = v.x + v.y, s2 = v.x * v.x + v.y * v.y;
  #pragma unroll
  for (int m = 1; m < 64; m <<= 1) { s += __shfl_xor(s, m, 64); s2 += __shfl_xor(s2, m, 64); }
  __shared__ float red[8];
  int w = tid >> 6;
  if ((tid & 63) == 0) { red[w * 2] = s; red[w * 2 + 1] = s2; }
  __syncthreads();
  float ts = red[0] + red[2] + red[4] + red[6];
  float ts2 = red[1] + red[3] + red[5] + red[7];
  float mu = ts * (1.0f / 512.0f);
  float rs = rsqrtf(ts2 * (1.0f / 512.0f) - mu * mu + 1e-5f);
  int c = tid * 2;
  ushort2 o;
  o.x = f2bf((v.x - mu) * rs * g[c] + bt[c]);
  o.y = f2bf((v.y - mu) * rs * g[c + 1] + bt[c + 1]);
  *(ushort2*)(out + (size_t)row * 512 + c) = o;
  if (oinit) {
    float2 oi; oi.x = v.x + badd[c]; oi.y = v.y + badd[c + 1];
    *(float2*)(oinit + (size_t)row * 512 + c) = oi;
  }
}

// ---------------- generic bf16 GEMM with k-range (split-K via blockIdx.z) ----------------
struct EpiQKV {
  unsigned short *q, *k, *v;
  const float *bq, *bk, *bv;
  __device__ void operator()(int m, int n, float val) const {
    int b = m >> 11, s = m & 2047;
    int which = n >> 9, col = n & 511;
    int h = col >> 6, d = col & 63;
    int bh = b * 8 + h;
    if (which == 0)      q[((size_t)bh * 2048 + s) * 64 + d] = f2bf((val + bq[col]) * QSCALE);
    else if (which == 1) k[((size_t)bh * 2048 + s) * 64 + d] = f2bf(val + bk[col]);
    else                 v[((size_t)bh * 2048 + s) * 64 + d] = f2bf(val + bv[col]);
  }
};
struct EpiAtomic {       // acc buffer pre-initialized with (residual + bias)
  float* dst; int ldn;
  __device__ void operator()(int m, int n, float val) const {
    atomicAdd(dst + (size_t)m * ldn + n, val);
  }
};
struct EpiGelu {
  const float* b1; unsigned short* h;
  __device__ void operator()(int m, int n, float val) const {
    float t = val + b1[n];
    float gl = 0.5f * t * (1.0f + erff(t * 0.70710678118654752f));
    h[(size_t)m * 2048 + n] = f2bf(gl);
  }
};

template <typename Epi>
__global__ __launch_bounds__(256) void gemm_bt(const unsigned short* __restrict__ A,
                                               const unsigned short* __restrict__ Bt,
                                               int lda, int ldb, int kchunk, Epi epi) {
  __shared__ unsigned short a_lds[128 * 32];
  __shared__ unsigned short b_lds[128 * 32];
  const int tid = threadIdx.x;
  const int lane = tid & 63;
  const int w = tid >> 6;
  const int l15 = lane & 15, quad = lane >> 4;
  const int wm = w >> 1, wn = w & 1;
  const int m0 = blockIdx.y * 128, n0 = blockIdx.x * 128;
  const int K0 = blockIdx.z * kchunk, K1 = K0 + kchunk;

  f32x4 acc[4][4] = {};

  for (int k0 = K0; k0 < K1; k0 += 32) {
    __syncthreads();
    #pragma unroll
    for (int i = 0; i < 2; i++) {
      int c = tid + i * 256;
      int g = c >> 6;
      int row = g * 16 + l15;
      int col = quad * 8;
      gll16(A + (size_t)(m0 + row) * lda + k0 + col, a_lds + (size_t)(c & ~63) * 8);
      gll16(Bt + (size_t)(n0 + row) * ldb + k0 + col, b_lds + (size_t)(c & ~63) * 8);
    }
    __syncthreads();
    bf16x8 af[4], bfr[4];
    #pragma unroll
    for (int t = 0; t < 4; t++) {
      af[t]  = *(const bf16x8*)(a_lds + ((size_t)(wm * 4 + t) * 64 + lane) * 8);
      bfr[t] = *(const bf16x8*)(b_lds + ((size_t)(wn * 4 + t) * 64 + lane) * 8);
    }
    #pragma unroll
    for (int mt = 0; mt < 4; mt++)
      #pragma unroll
      for (int nt = 0; nt < 4; nt++)
        acc[mt][nt] = __builtin_amdgcn_mfma_f32_16x16x32_bf16(af[mt], bfr[nt], acc[mt][nt], 0, 0, 0);
  }
  #pragma unroll
  for (int mt = 0; mt < 4; mt++)
    #pragma unroll
    for (int nt = 0; nt < 4; nt++)
      #pragma unroll
      for (int r = 0; r < 4; r++)
        epi(m0 + wm * 64 + mt * 16 + quad * 4 + r, n0 + wn * 64 + nt * 16 + l15, acc[mt][nt][r]);
}

// ---------------- V transpose: vb[bh][s][d] -> vbT[bh][d][s], 64x64 tiles ----------------
__global__ __launch_bounds__(256) void vt_kernel(const unsigned short* __restrict__ vb,
                                                 unsigned short* __restrict__ vbT) {
  __shared__ unsigned short tile[64][72];
  const int bh = blockIdx.y, s0 = blockIdx.x * 64;
  const int tid = threadIdx.x;
  const unsigned short* src = vb + ((size_t)bh * 2048 + s0) * 64;
  #pragma unroll
  for (int i = 0; i < 2; i++) {
    int r = (tid >> 3) + i * 32;
    int c8 = (tid & 7) * 8;
    *(uint4*)(&tile[r][c8]) = *(const uint4*)(src + (size_t)r * 64 + c8);
  }
  __syncthreads();
  unsigned short* dst = vbT + (size_t)bh * 64 * 2048 + s0;
  #pragma unroll
  for (int i = 0; i < 2; i++) {
    int d = (tid >> 3) + i * 32;
    int s8 = (tid & 7) * 8;
    ushort4 o0, o1;
    o0.x = tile[s8 + 0][d]; o0.y = tile[s8 + 1][d]; o0.z = tile[s8 + 2][d]; o0.w = tile[s8 + 3][d];
    o1.x = tile[s8 + 4][d]; o1.y = tile[s8 + 5][d]; o1.z = tile[s8 + 6][d]; o1.w = tile[s8 + 7][d];
    *(ushort4*)(dst + (size_t)d * 2048 + s8) = o0;
    *(ushort4*)(dst + (size_t)d * 2048 + s8 + 4) = o1;
  }
}

// ---------------- flash attention v2: no-max softmax, bias as MFMA C, key-split ----------------
// block = 128 q rows (4 waves x 32 q, 2 groups of 16), 64-key tiles, split over key halves.
// Emits unnormalized O partials (fp32) + per-row l partials.
__global__ __launch_bounds__(256) void attn_kernel(const unsigned short* __restrict__ Q,
                                                   const unsigned short* __restrict__ Kb,
                                                   const unsigned short* __restrict__ VT,
                                                   const unsigned short* __restrict__ biasp,
                                                   float* __restrict__ o_part,
                                                   float* __restrict__ l_part) {
  __shared__ unsigned short k_lds[64 * 64];
  __shared__ unsigned short v_lds[64 * 64];
  __shared__ unsigned short bias_lds[128 * 72];
  __shared__ unsigned short p_lds[4][2][16 * 72];

  const int tid = threadIdx.x;
  const int lane = tid & 63, w = tid >> 6;
  const int l15 = lane & 15, quad = lane >> 4;
  const int bh = blockIdx.x, b = bh >> 3;
  const int q0 = blockIdx.y * 128;
  const int split = blockIdx.z;

  bf16x8 qf[2][2];
  #pragma unroll
  for (int g = 0; g < 2; g++) {
    const unsigned short* qrow = Q + ((size_t)bh * 2048 + q0 + w * 32 + g * 16 + l15) * 64;
    qf[g][0] = *(const bf16x8*)(qrow + quad * 8);
    qf[g][1] = *(const bf16x8*)(qrow + 32 + quad * 8);
  }

  f32x4 o_acc[2][4] = {};
  float l_acc[2] = {0.0f, 0.0f};

  const unsigned short* kbase = Kb + (size_t)bh * 2048 * 64;
  const unsigned short* vbase = VT + (size_t)bh * 64 * 2048;
  const unsigned short* bbase = biasp + ((size_t)b * 2048 + q0) * 2048;

  const int kt0 = split * 16, kt1 = kt0 + 16;
  for (int kt = kt0; kt < kt1; kt++) {
    const int kcol0 = kt * 64;
    __syncthreads();
    #pragma unroll
    for (int i = 0; i < 2; i++) {
      int c = tid + i * 256;
      int g = c >> 6;
      int mt = g >> 1, kk = g & 1;
      int rr = mt * 16 + l15;
      int cc = kk * 32 + quad * 8;
      gll16(kbase + (size_t)(kcol0 + rr) * 64 + cc, k_lds + (size_t)(c & ~63) * 8);
      gll16(vbase + (size_t)rr * 2048 + kcol0 + cc, v_lds + (size_t)(c & ~63) * 8);
    }
    #pragma unroll
    for (int i = 0; i < 4; i++) {
      int r = (tid >> 3) + i * 32;
      int c8 = (tid & 7) * 8;
      uint4 dv = *(const uint4*)(bbase + (size_t)r * 2048 + kcol0 + c8);
      *(uint4*)(bias_lds + r * 72 + c8) = dv;
    }
    __syncthreads();

    bf16x8 af[4][2];
    #pragma unroll
    for (int mt = 0; mt < 4; mt++) {
      af[mt][0] = *(const bf16x8*)(k_lds + ((size_t)(mt * 2 + 0) * 64 + lane) * 8);
      af[mt][1] = *(const bf16x8*)(k_lds + ((size_t)(mt * 2 + 1) * 64 + lane) * 8);
    }

    // scores + exp2 + P pack (per q-group)
    #pragma unroll
    for (int g = 0; g < 2; g++) {
      const int qrow = w * 32 + g * 16 + l15;
      #pragma unroll
      for (int mt = 0; mt < 4; mt++) {
        ushort4 bl = *(const ushort4*)(bias_lds + (size_t)qrow * 72 + mt * 16 + quad * 4);
        f32x4 cb; cb[0] = bf2f(bl.x); cb[1] = bf2f(bl.y); cb[2] = bf2f(bl.z); cb[3] = bf2f(bl.w);
        f32x4 accv = __builtin_amdgcn_mfma_f32_16x16x32_bf16(af[mt][0], qf[g][0], cb, 0, 0, 0);
        accv = __builtin_amdgcn_mfma_f32_16x16x32_bf16(af[mt][1], qf[g][1], accv, 0, 0, 0);
        float p0 = exp2f(accv[0]), p1 = exp2f(accv[1]);
        float p2 = exp2f(accv[2]), p3 = exp2f(accv[3]);
        l_acc[g] += (p0 + p1) + (p2 + p3);
        ushort4 pv;
        pv.x = f2bf_fast(p0); pv.y = f2bf_fast(p1); pv.z = f2bf_fast(p2); pv.w = f2bf_fast(p3);
        *(ushort4*)(p_lds[w][g] + l15 * 72 + mt * 16 + quad * 4) = pv;
      }
    }

    bf16x8 vf[4][2];
    #pragma unroll
    for (int dt = 0; dt < 4; dt++) {
      vf[dt][0] = *(const bf16x8*)(v_lds + ((size_t)(dt * 2 + 0) * 64 + lane) * 8);
      vf[dt][1] = *(const bf16x8*)(v_lds + ((size_t)(dt * 2 + 1) * 64 + lane) * 8);
    }
    #pragma unroll
    for (int g = 0; g < 2; g++) {
      bf16x8 pf0 = *(const bf16x8*)(p_lds[w][g] + l15 * 72 + quad * 8);
      bf16x8 pf1 = *(const bf16x8*)(p_lds[w][g] + l15 * 72 + 32 + quad * 8);
      #pragma unroll
      for (int dt = 0; dt < 4; dt++) {
        o_acc[g][dt] = __builtin_amdgcn_mfma_f32_16x16x32_bf16(pf0, vf[dt][0], o_acc[g][dt], 0, 0, 0);
        o_acc[g][dt] = __builtin_amdgcn_mfma_f32_16x16x32_bf16(pf1, vf[dt][1], o_acc[g][dt], 0, 0, 0);
      }
    }
  }

  const size_t obase = ((size_t)split * 16 + bh) * 2048;
  #pragma unroll
  for (int g = 0; g < 2; g++) {
    float l = l_acc[g];
    l += __shfl_xor(l, 16, 64);
    l += __shfl_xor(l, 32, 64);
    if (quad == 0) l_part[obase + q0 + w * 32 + g * 16 + l15] = l;
    #pragma unroll
    for (int dt = 0; dt < 4; dt++)
      #pragma unroll
      for (int r = 0; r < 4; r++)
        o_part[(obase + q0 + w * 32 + g * 16 + quad * 4 + r) * 64 + dt * 16 + l15] = o_acc[g][dt][r];
  }
}

// ---------------- combine: ao = bf16((O0+O1)/(l0+l1)); x1 = x + bo ----------------
__global__ __launch_bounds__(256) void combine_kernel(const float* __restrict__ o_part,
                                                      const float* __restrict__ l_part,
                                                      const float* __restrict__ x,
                                                      const float* __restrict__ bo,
                                                      unsigned short* __restrict__ ao,
                                                      float* __restrict__ x1) {
  const int row = blockIdx.x;           // b*2048 + s
  const int b = row >> 11, s = row & 2047;
  const int col = threadIdx.x * 2;
  const int h = col >> 6, d = col & 63;
  const int bh = b * 8 + h;
  const size_t i0 = ((size_t)bh * 2048 + s) * 64 + d;
  const size_t i1 = ((size_t)(16 + bh) * 2048 + s) * 64 + d;
  float2 a = *(const float2*)(o_part + i0);
  float2 c = *(const float2*)(o_part + i1);
  float l = l_part[(size_t)bh * 2048 + s] + l_part[(size_t)(16 + bh) * 2048 + s];
  float inv = 1.0f / l;
  ushort2 o;
  o.x = f2bf((a.x + c.x) * inv);
  o.y = f2bf((a.y + c.y) * inv);
  *(ushort2*)(ao + (size_t)row * 512 + col) = o;
  float2 xv = *(const float2*)(x + (size_t)row * 512 + col);
  float2 xo; xo.x = xv.x + bo[col]; xo.y = xv.y + bo[col + 1];
  *(float2*)(x1 + (size_t)row * 512 + col) = xo;
}

// ---------------- host launch ----------------
extern "C" void kernel_launch(void* const* d_in, const int* in_sizes, int n_in,
                              void* d_out, int out_size, void* d_ws, size_t ws_size,
                              hipStream_t stream) {
  (void)in_sizes; (void)n_in; (void)out_size; (void)ws_size;
  const float* x    = (const float*)d_in[0];
  const int*   adj  = (const int*)d_in[1];
  const float* edge = (const float*)d_in[2];
  const float* ln1g = (const float*)d_in[3];
  const float* ln1b = (const float*)d_in[4];
  const float* ln2g = (const float*)d_in[5];
  const float* ln2b = (const float*)d_in[6];
  const float* wq = (const float*)d_in[7];  const float* bq = (const float*)d_in[8];
  const float* wk = (const float*)d_in[9];  const float* bk = (const float*)d_in[10];
  const float* wv = (const float*)d_in[11]; const float* bv = (const float*)d_in[12];
  const float* wo = (const float*)d_in[13]; const float* bo = (const float*)d_in[14];
  const float* w1 = (const float*)d_in[15]; const float* b1 = (const float*)d_in[16];
  const float* w2 = (const float*)d_in[17]; const float* b2 = (const float*)d_in[18];
  float* out = (float*)d_out;

  char* ws = (char*)d_ws;
  unsigned short* qkvT = (unsigned short*)ws; ws += (size_t)1536 * 512 * 2;
  unsigned short* woT  = (unsigned short*)ws; ws += (size_t)512 * 512 * 2;
  unsigned short* w1T  = (unsigned short*)ws; ws += (size_t)2048 * 512 * 2;
  unsigned short* w2T  = (unsigned short*)ws; ws += (size_t)512 * 2048 * 2;
  unsigned short* bp   = (unsigned short*)ws; ws += (size_t)2 * 2048 * 2048 * 2;
  unsigned short* nx   = (unsigned short*)ws; ws += (size_t)4096 * 512 * 2;
  unsigned short* qb   = (unsigned short*)ws; ws += (size_t)16 * 2048 * 64 * 2;
  unsigned short* kb   = (unsigned short*)ws; ws += (size_t)16 * 2048 * 64 * 2;
  unsigned short* vb   = (unsigned short*)ws; ws += (size_t)16 * 2048 * 64 * 2;
  unsigned short* vbT  = (unsigned short*)ws; ws += (size_t)16 * 64 * 2048 * 2;
  unsigned short* ao   = (unsigned short*)ws; ws += (size_t)4096 * 512 * 2;
  float*          x1   = (float*)ws;          ws += (size_t)4096 * 512 * 4;
  unsigned short* n2   = (unsigned short*)ws; ws += (size_t)4096 * 512 * 2;
  float*          lpt  = (float*)ws;          ws += (size_t)2 * 16 * 2048 * 4;
  float*          opt  = (float*)ws;          // 2*16*2048*64*4 = 16.8MB, reused as hb
  unsigned short* hb   = (unsigned short*)opt;

  dim3 blk(256);
  TP4 tp; tp.in[0] = wq; tp.in[1] = wk; tp.in[2] = wv; tp.in[3] = wo;
  tp.out[0] = qkvT; tp.out[1] = qkvT + (size_t)512 * 512;
  tp.out[2] = qkvT + (size_t)2 * 512 * 512; tp.out[3] = woT;
  transpose_cast4<<<dim3(16, 16, 4), blk, 0, stream>>>(tp);
  transpose_cast<<<dim3(64, 16), blk, 0, stream>>>(w1, w1T, 512, 2048);
  transpose_cast<<<dim3(16, 64), blk, 0, stream>>>(w2, w2T, 2048, 512);
  bias_pack<<<8192, blk, 0, stream>>>(adj, edge, bp);
  ln_kernel<<<4096, blk, 0, stream>>>(x, ln1g, ln1b, nx, nullptr, nullptr);
  gemm_bt<<<dim3(12, 32, 1), blk, 0, stream>>>(nx, qkvT, 512, 512, 512,
                                               EpiQKV{qb, kb, vb, bq, bk, bv});
  vt_kernel<<<dim3(32, 16), blk, 0, stream>>>(vb, vbT);
  attn_kernel<<<dim3(16, 16, 2), blk, 0, stream>>>(qb, kb, vbT, bp, opt, lpt);
  combine_kernel<<<4096, blk, 0, stream>>>(opt, lpt, x, bo, ao, x1);
  gemm_bt<<<dim3(4, 32, 2), blk, 0, stream>>>(ao, woT, 512, 512, 256,
                                              EpiAtomic{x1, 512});
  ln_kernel<<<4096, blk, 0, stream>>>(x1, ln2g, ln2b, n2, b2, out);
  gemm_bt<<<dim3(16, 32, 1), blk, 0, stream>>>(n2, w1T, 512, 512, 512,
                                               EpiGelu{b1, hb});
  gemm_bt<<<dim3(4, 32, 4), blk, 0, stream>>>(hb, w2T, 2048, 2048, 512,
                                              EpiAtomic{out, 512});
}

// Round 3
// 321.660 us; speedup vs baseline: 1.3122x; 1.1099x over previous
//
#include <hip/hip_runtime.h>
#include <cstdint>
#include <cstddef>

typedef __bf16 bf16x8 __attribute__((ext_vector_type(8)));
typedef float f32x4 __attribute__((ext_vector_type(4)));
typedef const __attribute__((address_space(1))) void* gas_t;
typedef __attribute__((address_space(3))) void* las_t;

#define QSCALE 0.18033688011112042f   /* 0.125 * log2(e) */
#define BSCALE 0.14426950408889634f   /* 0.1 * log2(e)   */

__device__ __forceinline__ unsigned short f2bf(float f) {
  union { float f; unsigned u; } v; v.f = f;
  unsigned r = v.u + 0x7FFFu + ((v.u >> 16) & 1u);   // RNE
  return (unsigned short)(r >> 16);
}
__device__ __forceinline__ unsigned short f2bf_fast(float f) {
  union { float f; unsigned u; } v; v.f = f;
  return (unsigned short)((v.u + 0x8000u) >> 16);    // round-nearest-away (p>=0)
}
__device__ __forceinline__ float bf2f(unsigned short h) {
  union { unsigned u; float f; } v; v.u = ((unsigned)h) << 16;
  return v.f;
}
__device__ __forceinline__ void gll16(const void* g, void* l) {
  __builtin_amdgcn_global_load_lds((gas_t)g, (las_t)l, 16, 0, 0);
}

// ---------------- weight transpose + bf16 cast:  out[C][R] = bf16(in[R][C]) ----------------
__global__ __launch_bounds__(256) void transpose_cast(const float* __restrict__ in,
                                                      unsigned short* __restrict__ out,
                                                      int R, int C) {
  __shared__ float tile[32][33];
  int bx = blockIdx.x * 32, by = blockIdx.y * 32;
  int tx = threadIdx.x & 31, tg = threadIdx.x >> 5;
  #pragma unroll
  for (int i = 0; i < 4; i++) {
    int r = tg * 4 + i;
    tile[r][tx] = in[(size_t)(by + r) * C + bx + tx];
  }
  __syncthreads();
  #pragma unroll
  for (int i = 0; i < 4; i++) {
    int r = tg * 4 + i;
    out[(size_t)(bx + r) * R + by + tx] = f2bf(tile[tx][r]);
  }
}

struct TP4 { const float* in[4]; unsigned short* out[4]; };
__global__ __launch_bounds__(256) void transpose_cast4(TP4 p) {  // 512x512 each
  __shared__ float tile[32][33];
  const float* in = p.in[blockIdx.z];
  unsigned short* out = p.out[blockIdx.z];
  int bx = blockIdx.x * 32, by = blockIdx.y * 32;
  int tx = threadIdx.x & 31, tg = threadIdx.x >> 5;
  #pragma unroll
  for (int i = 0; i < 4; i++) {
    int r = tg * 4 + i;
    tile[r][tx] = in[(size_t)(by + r) * 512 + bx + tx];
  }
  __syncthreads();
  #pragma unroll
  for (int i = 0; i < 4; i++) {
    int r = tg * 4 + i;
    out[(size_t)(bx + r) * 512 + by + tx] = f2bf(tile[tx][r]);
  }
}

// ---------------- bias pack: bf16( adj>0 ? 0.1*edge*adj*log2e - 20 : -30000 ) ----------------
__global__ __launch_bounds__(256) void bias_pack(const int* __restrict__ adj,
                                                 const float* __restrict__ edge,
                                                 unsigned short* __restrict__ bp) {
  size_t i = ((size_t)blockIdx.x * 256 + threadIdx.x) * 4;
  int4 a = *(const int4*)(adj + i);
  float4 e = *(const float4*)(edge + i);
  ushort4 r;
  r.x = a.x > 0 ? f2bf(BSCALE * e.x * (float)a.x - 20.0f) : f2bf(-30000.0f);
  r.y = a.y > 0 ? f2bf(BSCALE * e.y * (float)a.y - 20.0f) : f2bf(-30000.0f);
  r.z = a.z > 0 ? f2bf(BSCALE * e.z * (float)a.z - 20.0f) : f2bf(-30000.0f);
  r.w = a.w > 0 ? f2bf(BSCALE * e.w * (float)a.w - 20.0f) : f2bf(-30000.0f);
  *(ushort4*)(bp + i) = r;
}

// ---------------- LayerNorm over D=512 (ln1) ----------------
__global__ __launch_bounds__(256) void ln_kernel(const float* __restrict__ x,
                                                 const float* __restrict__ g,
                                                 const float* __restrict__ bt,
                                                 unsigned short* __restrict__ out) {
  int row = blockIdx.x, tid = threadIdx.x;
  float2 v = *(const float2*)(x + (size_t)row * 512 + tid * 2);
  float s = v.x + v.y, s2 = v.x * v.x + v.y * v.y;
  #pragma unroll
  for (int m = 1; m < 64; m <<= 1) { s += __shfl_xor(s, m, 64); s2 += __shfl_xor(s2, m, 64); }
  __shared__ float red[8];
  int w = tid >> 6;
  if ((tid & 63) == 0) { red[w * 2] = s; red[w * 2 + 1] = s2; }
  __syncthreads();
  float ts = red[0] + red[2] + red[4] + red[6];
  float ts2 = red[1] + red[3] + red[5] + red[7];
  float mu = ts * (1.0f / 512.0f);
  float rs = rsqrtf(ts2 * (1.0f / 512.0f) - mu * mu + 1e-5f);
  int c = tid * 2;
  ushort2 o;
  o.x = f2bf((v.x - mu) * rs * g[c] + bt[c]);
  o.y = f2bf((v.y - mu) * rs * g[c + 1] + bt[c + 1]);
  *(ushort2*)(out + (size_t)row * 512 + c) = o;
}

// ---- fused: x1 = x + bo + p0 + p1 (bf16 partials); then LN -> n2; also store x1 fp32 ----
__global__ __launch_bounds__(256) void ln_fuse2(const float* __restrict__ x,
                                                const unsigned short* __restrict__ opp,
                                                const float* __restrict__ bo,
                                                const float* __restrict__ g,
                                                const float* __restrict__ bt,
                                                float* __restrict__ x1,
                                                unsigned short* __restrict__ n2) {
  const size_t MN = (size_t)4096 * 512;
  int row = blockIdx.x, tid = threadIdx.x;
  int c = tid * 2;
  size_t idx = (size_t)row * 512 + c;
  float2 xv = *(const float2*)(x + idx);
  ushort2 p0 = *(const ushort2*)(opp + idx);
  ushort2 p1 = *(const ushort2*)(opp + MN + idx);
  float2 v;
  v.x = xv.x + bo[c]     + bf2f(p0.x) + bf2f(p1.x);
  v.y = xv.y + bo[c + 1] + bf2f(p0.y) + bf2f(p1.y);
  float s = v.x + v.y, s2 = v.x * v.x + v.y * v.y;
  #pragma unroll
  for (int m = 1; m < 64; m <<= 1) { s += __shfl_xor(s, m, 64); s2 += __shfl_xor(s2, m, 64); }
  __shared__ float red[8];
  int w = tid >> 6;
  if ((tid & 63) == 0) { red[w * 2] = s; red[w * 2 + 1] = s2; }
  __syncthreads();
  float ts = red[0] + red[2] + red[4] + red[6];
  float ts2 = red[1] + red[3] + red[5] + red[7];
  float mu = ts * (1.0f / 512.0f);
  float rs = rsqrtf(ts2 * (1.0f / 512.0f) - mu * mu + 1e-5f);
  *(float2*)(x1 + idx) = v;
  ushort2 o;
  o.x = f2bf((v.x - mu) * rs * g[c] + bt[c]);
  o.y = f2bf((v.y - mu) * rs * g[c + 1] + bt[c + 1]);
  *(ushort2*)(n2 + idx) = o;
}

// ---------------- final: out = x1 + b2 + sum of 4 bf16 partials ----------------
__global__ __launch_bounds__(256) void final_combine(const float* __restrict__ x1,
                                                     const float* __restrict__ b2,
                                                     const unsigned short* __restrict__ mp,
                                                     float* __restrict__ out) {
  const size_t MN = (size_t)4096 * 512;
  size_t i = ((size_t)blockIdx.x * 256 + threadIdx.x) * 4;
  float4 xv = *(const float4*)(x1 + i);
  float4 bv = *(const float4*)(b2 + (i & 511));
  float4 a;
  a.x = xv.x + bv.x; a.y = xv.y + bv.y; a.z = xv.z + bv.z; a.w = xv.w + bv.w;
  #pragma unroll
  for (int sp = 0; sp < 4; sp++) {
    ushort4 p = *(const ushort4*)(mp + sp * MN + i);
    a.x += bf2f(p.x); a.y += bf2f(p.y); a.z += bf2f(p.z); a.w += bf2f(p.w);
  }
  *(float4*)(out + i) = a;
}

// ---------------- generic bf16 GEMM, BK=64, split-K via blockIdx.z ----------------
struct EpiQKV {
  unsigned short *q, *k, *v;
  const float *bq, *bk, *bv;
  __device__ void operator()(int m, int n, float val) const {
    int b = m >> 11, s = m & 2047;
    int which = n >> 9, col = n & 511;
    int h = col >> 6, d = col & 63;
    int bh = b * 8 + h;
    if (which == 0)      q[((size_t)bh * 2048 + s) * 64 + d] = f2bf((val + bq[col]) * QSCALE);
    else if (which == 1) k[((size_t)bh * 2048 + s) * 64 + d] = f2bf(val + bk[col]);
    else                 v[((size_t)bh * 2048 + s) * 64 + d] = f2bf(val + bv[col]);
  }
};
struct EpiPart {     // bf16 partials, one chunk per split
  unsigned short* dst; int ldn;
  __device__ void operator()(int m, int n, float val) const {
    dst[(size_t)blockIdx.z * 4096 * 512 + (size_t)m * ldn + n] = f2bf(val);
  }
};
struct EpiGelu {
  const float* b1; unsigned short* h;
  __device__ void operator()(int m, int n, float val) const {
    float t = val + b1[n];
    float gl = 0.5f * t * (1.0f + erff(t * 0.70710678118654752f));
    h[(size_t)m * 2048 + n] = f2bf(gl);
  }
};

template <typename Epi>
__global__ __launch_bounds__(256) void gemm_bt(const unsigned short* __restrict__ A,
                                               const unsigned short* __restrict__ Bt,
                                               int lda, int ldb, int kchunk, Epi epi) {
  __shared__ unsigned short a_lds[128 * 64];
  __shared__ unsigned short b_lds[128 * 64];
  const int tid = threadIdx.x;
  const int lane = tid & 63;
  const int w = tid >> 6;
  const int l15 = lane & 15, quad = lane >> 4;
  const int wm = w >> 1, wn = w & 1;
  const int m0 = blockIdx.y * 128, n0 = blockIdx.x * 128;
  const int K0 = blockIdx.z * kchunk, K1 = K0 + kchunk;

  f32x4 acc[4][4] = {};

  for (int k0 = K0; k0 < K1; k0 += 64) {
    __syncthreads();
    #pragma unroll
    for (int i = 0; i < 4; i++) {
      int c = tid + i * 256;
      int g = c >> 6;                      // 0..15
      int row = (g >> 1) * 16 + l15;
      int col = (g & 1) * 32 + quad * 8;
      gll16(A + (size_t)(m0 + row) * lda + k0 + col, a_lds + (size_t)(c & ~63) * 8);
      gll16(Bt + (size_t)(n0 + row) * ldb + k0 + col, b_lds + (size_t)(c & ~63) * 8);
    }
    __syncthreads();
    bf16x8 af[4][2], bfr[4][2];
    #pragma unroll
    for (int t = 0; t < 4; t++)
      #pragma unroll
      for (int ks = 0; ks < 2; ks++) {
        af[t][ks]  = *(const bf16x8*)(a_lds + (((size_t)(wm * 4 + t) * 2 + ks) * 64 + lane) * 8);
        bfr[t][ks] = *(const bf16x8*)(b_lds + (((size_t)(wn * 4 + t) * 2 + ks) * 64 + lane) * 8);
      }
    #pragma unroll
    for (int mt = 0; mt < 4; mt++)
      #pragma unroll
      for (int nt = 0; nt < 4; nt++) {
        acc[mt][nt] = __builtin_amdgcn_mfma_f32_16x16x32_bf16(af[mt][0], bfr[nt][0], acc[mt][nt], 0, 0, 0);
        acc[mt][nt] = __builtin_amdgcn_mfma_f32_16x16x32_bf16(af[mt][1], bfr[nt][1], acc[mt][nt], 0, 0, 0);
      }
  }
  #pragma unroll
  for (int mt = 0; mt < 4; mt++)
    #pragma unroll
    for (int nt = 0; nt < 4; nt++)
      #pragma unroll
      for (int r = 0; r < 4; r++)
        epi(m0 + wm * 64 + mt * 16 + quad * 4 + r, n0 + wn * 64 + nt * 16 + l15, acc[mt][nt][r]);
}

// ---------------- V transpose: vb[bh][s][d] -> vbT[bh][d][s], 64x64 tiles ----------------
__global__ __launch_bounds__(256) void vt_kernel(const unsigned short* __restrict__ vb,
                                                 unsigned short* __restrict__ vbT) {
  __shared__ unsigned short tile[64][72];
  const int bh = blockIdx.y, s0 = blockIdx.x * 64;
  const int tid = threadIdx.x;
  const unsigned short* src = vb + ((size_t)bh * 2048 + s0) * 64;
  #pragma unroll
  for (int i = 0; i < 2; i++) {
    int r = (tid >> 3) + i * 32;
    int c8 = (tid & 7) * 8;
    *(uint4*)(&tile[r][c8]) = *(const uint4*)(src + (size_t)r * 64 + c8);
  }
  __syncthreads();
  unsigned short* dst = vbT + (size_t)bh * 64 * 2048 + s0;
  #pragma unroll
  for (int i = 0; i < 2; i++) {
    int d = (tid >> 3) + i * 32;
    int s8 = (tid & 7) * 8;
    ushort4 o0, o1;
    o0.x = tile[s8 + 0][d]; o0.y = tile[s8 + 1][d]; o0.z = tile[s8 + 2][d]; o0.w = tile[s8 + 3][d];
    o1.x = tile[s8 + 4][d]; o1.y = tile[s8 + 5][d]; o1.z = tile[s8 + 6][d]; o1.w = tile[s8 + 7][d];
    *(ushort4*)(dst + (size_t)d * 2048 + s8) = o0;
    *(ushort4*)(dst + (size_t)d * 2048 + s8 + 4) = o1;
  }
}

// ---------------- flash attention v3: bias direct to C-operand, split 4, 4 blocks/CU ----------------
__global__ __launch_bounds__(256, 4) void attn_kernel(const unsigned short* __restrict__ Q,
                                                      const unsigned short* __restrict__ Kb,
                                                      const unsigned short* __restrict__ VT,
                                                      const unsigned short* __restrict__ biasp,
                                                      unsigned short* __restrict__ o_part,
                                                      float* __restrict__ l_part) {
  __shared__ unsigned short k_lds[64 * 64];
  __shared__ unsigned short v_lds[64 * 64];
  __shared__ unsigned short p_lds[4][2][16 * 72];

  const int tid = threadIdx.x;
  const int lane = tid & 63, w = tid >> 6;
  const int l15 = lane & 15, quad = lane >> 4;
  const int bh = blockIdx.x, b = bh >> 3;
  const int q0 = blockIdx.y * 128;
  const int split = blockIdx.z;

  bf16x8 qf[2][2];
  const unsigned short* brow[2];
  #pragma unroll
  for (int g = 0; g < 2; g++) {
    const unsigned short* qrow = Q + ((size_t)bh * 2048 + q0 + w * 32 + g * 16 + l15) * 64;
    qf[g][0] = *(const bf16x8*)(qrow + quad * 8);
    qf[g][1] = *(const bf16x8*)(qrow + 32 + quad * 8);
    brow[g] = biasp + ((size_t)b * 2048 + q0 + w * 32 + g * 16 + l15) * 2048;
  }

  f32x4 o_acc[2][4] = {};
  float l_acc[2] = {0.0f, 0.0f};

  const unsigned short* kbase = Kb + (size_t)bh * 2048 * 64;
  const unsigned short* vbase = VT + (size_t)bh * 64 * 2048;

  const int kt0 = split * 8, kt1 = kt0 + 8;
  for (int kt = kt0; kt < kt1; kt++) {
    const int kcol0 = kt * 64;
    __syncthreads();
    #pragma unroll
    for (int i = 0; i < 2; i++) {
      int c = tid + i * 256;
      int g = c >> 6;
      int mt = g >> 1, kk = g & 1;
      int rr = mt * 16 + l15;
      int cc = kk * 32 + quad * 8;
      gll16(kbase + (size_t)(kcol0 + rr) * 64 + cc, k_lds + (size_t)(c & ~63) * 8);
      gll16(vbase + (size_t)rr * 2048 + kcol0 + cc, v_lds + (size_t)(c & ~63) * 8);
    }
    // bias direct to registers (C-operand layout: 4 consecutive keys per lane)
    ushort4 bl[2][4];
    #pragma unroll
    for (int g = 0; g < 2; g++)
      #pragma unroll
      for (int mt = 0; mt < 4; mt++)
        bl[g][mt] = *(const ushort4*)(brow[g] + kcol0 + mt * 16 + quad * 4);
    __syncthreads();

    // scores: S^T tiles [16 keys x 16 q], bias as C input
    #pragma unroll
    for (int mt = 0; mt < 4; mt++) {
      bf16x8 a0 = *(const bf16x8*)(k_lds + ((size_t)(mt * 2 + 0) * 64 + lane) * 8);
      bf16x8 a1 = *(const bf16x8*)(k_lds + ((size_t)(mt * 2 + 1) * 64 + lane) * 8);
      #pragma unroll
      for (int g = 0; g < 2; g++) {
        f32x4 cb;
        cb[0] = bf2f(bl[g][mt].x); cb[1] = bf2f(bl[g][mt].y);
        cb[2] = bf2f(bl[g][mt].z); cb[3] = bf2f(bl[g][mt].w);
        f32x4 accv = __builtin_amdgcn_mfma_f32_16x16x32_bf16(a0, qf[g][0], cb, 0, 0, 0);
        accv = __builtin_amdgcn_mfma_f32_16x16x32_bf16(a1, qf[g][1], accv, 0, 0, 0);
        float p0 = exp2f(accv[0]), p1 = exp2f(accv[1]);
        float p2 = exp2f(accv[2]), p3 = exp2f(accv[3]);
        l_acc[g] += (p0 + p1) + (p2 + p3);
        ushort4 pv;
        pv.x = f2bf_fast(p0); pv.y = f2bf_fast(p1); pv.z = f2bf_fast(p2); pv.w = f2bf_fast(p3);
        *(ushort4*)(p_lds[w][g] + l15 * 72 + mt * 16 + quad * 4) = pv;
      }
    }

    bf16x8 pf[2][2];
    #pragma unroll
    for (int g = 0; g < 2; g++) {
      pf[g][0] = *(const bf16x8*)(p_lds[w][g] + l15 * 72 + quad * 8);
      pf[g][1] = *(const bf16x8*)(p_lds[w][g] + l15 * 72 + 32 + quad * 8);
    }
    #pragma unroll
    for (int dt = 0; dt < 4; dt++) {
      bf16x8 v0 = *(const bf16x8*)(v_lds + ((size_t)(dt * 2 + 0) * 64 + lane) * 8);
      bf16x8 v1 = *(const bf16x8*)(v_lds + ((size_t)(dt * 2 + 1) * 64 + lane) * 8);
      #pragma unroll
      for (int g = 0; g < 2; g++) {
        o_acc[g][dt] = __builtin_amdgcn_mfma_f32_16x16x32_bf16(pf[g][0], v0, o_acc[g][dt], 0, 0, 0);
        o_acc[g][dt] = __builtin_amdgcn_mfma_f32_16x16x32_bf16(pf[g][1], v1, o_acc[g][dt], 0, 0, 0);
      }
    }
  }

  const size_t obase = ((size_t)split * 16 + bh) * 2048;
  #pragma unroll
  for (int g = 0; g < 2; g++) {
    float l = l_acc[g];
    l += __shfl_xor(l, 16, 64);
    l += __shfl_xor(l, 32, 64);
    if (quad == 0) l_part[obase + q0 + w * 32 + g * 16 + l15] = l;
    #pragma unroll
    for (int dt = 0; dt < 4; dt++)
      #pragma unroll
      for (int r = 0; r < 4; r++)
        o_part[(obase + q0 + w * 32 + g * 16 + quad * 4 + r) * 64 + dt * 16 + l15] =
            f2bf(o_acc[g][dt][r]);
  }
}

// ---------------- combine: ao = bf16( sum_sp O_sp / sum_sp l_sp ) ----------------
__global__ __launch_bounds__(256) void combine_kernel(const unsigned short* __restrict__ o_part,
                                                      const float* __restrict__ l_part,
                                                      unsigned short* __restrict__ ao) {
  const int row = blockIdx.x;           // b*2048 + s
  const int b = row >> 11, s = row & 2047;
  const int col = threadIdx.x * 2;
  const int h = col >> 6, d = col & 63;
  const int bh = b * 8 + h;
  float ox = 0.0f, oy = 0.0f, l = 0.0f;
  #pragma unroll
  for (int sp = 0; sp < 4; sp++) {
    size_t base = (size_t)(sp * 16 + bh) * 2048 + s;
    ushort2 o = *(const ushort2*)(o_part + base * 64 + d);
    ox += bf2f(o.x); oy += bf2f(o.y);
    l += l_part[base];
  }
  float inv = 1.0f / l;
  ushort2 o;
  o.x = f2bf(ox * inv);
  o.y = f2bf(oy * inv);
  *(ushort2*)(ao + (size_t)row * 512 + col) = o;
}

// ---------------- host launch ----------------
extern "C" void kernel_launch(void* const* d_in, const int* in_sizes, int n_in,
                              void* d_out, int out_size, void* d_ws, size_t ws_size,
                              hipStream_t stream) {
  (void)in_sizes; (void)n_in; (void)out_size; (void)ws_size;
  const float* x    = (const float*)d_in[0];
  const int*   adj  = (const int*)d_in[1];
  const float* edge = (const float*)d_in[2];
  const float* ln1g = (const float*)d_in[3];
  const float* ln1b = (const float*)d_in[4];
  const float* ln2g = (const float*)d_in[5];
  const float* ln2b = (const float*)d_in[6];
  const float* wq = (const float*)d_in[7];  const float* bq = (const float*)d_in[8];
  const float* wk = (const float*)d_in[9];  const float* bk = (const float*)d_in[10];
  const float* wv = (const float*)d_in[11]; const float* bv = (const float*)d_in[12];
  const float* wo = (const float*)d_in[13]; const float* bo = (const float*)d_in[14];
  const float* w1 = (const float*)d_in[15]; const float* b1 = (const float*)d_in[16];
  const float* w2 = (const float*)d_in[17]; const float* b2 = (const float*)d_in[18];
  float* out = (float*)d_out;

  // --- workspace layout (aliased; temporally disjoint uses) -----------------
  char* ws = (char*)d_ws;
  unsigned short* qkvT = (unsigned short*)ws; ws += (size_t)1536 * 512 * 2;
  unsigned short* woT  = (unsigned short*)ws; ws += (size_t)512 * 512 * 2;
  unsigned short* w1T  = (unsigned short*)ws; ws += (size_t)2048 * 512 * 2;
  unsigned short* w2T  = (unsigned short*)ws; ws += (size_t)512 * 2048 * 2;
  // bp (bf16 2*2048*2048, dead after attn)  ||  opp (bf16 2 outproj partials)
  unsigned short* bp   = (unsigned short*)ws;
  unsigned short* opp  = (unsigned short*)ws; ws += (size_t)2 * 2048 * 2048 * 2;
  // nx (dead after QKV gemm) || n2
  unsigned short* nx   = (unsigned short*)ws;
  unsigned short* n2   = (unsigned short*)ws; ws += (size_t)4096 * 512 * 2;
  // qb (dead after attn) || ao
  unsigned short* qb   = (unsigned short*)ws;
  unsigned short* ao   = (unsigned short*)ws; ws += (size_t)4096 * 512 * 2;
  unsigned short* kb   = (unsigned short*)ws; ws += (size_t)4096 * 512 * 2;
  // vb+vbT (dead after attn) || x1 (fp32)
  unsigned short* vb   = (unsigned short*)ws;
  float*          x1   = (float*)ws;          ws += (size_t)4096 * 512 * 2;
  unsigned short* vbT  = (unsigned short*)ws; ws += (size_t)4096 * 512 * 2;
  // region1: [opt bf16 16.78MB | lpt 0.5MB] (dead after combine) || [hb 16.78MB | mp 16.78MB]
  char* region1 = ws;
  unsigned short* opt  = (unsigned short*)region1;
  unsigned short* hb   = (unsigned short*)region1;
  float*          lpt  = (float*)(region1 + (size_t)4 * 16 * 2048 * 64 * 2);
  unsigned short* mp   = (unsigned short*)(region1 + (size_t)4 * 16 * 2048 * 64 * 2);

  dim3 blk(256);
  TP4 tp; tp.in[0] = wq; tp.in[1] = wk; tp.in[2] = wv; tp.in[3] = wo;
  tp.out[0] = qkvT; tp.out[1] = qkvT + (size_t)512 * 512;
  tp.out[2] = qkvT + (size_t)2 * 512 * 512; tp.out[3] = woT;
  transpose_cast4<<<dim3(16, 16, 4), blk, 0, stream>>>(tp);
  transpose_cast<<<dim3(64, 16), blk, 0, stream>>>(w1, w1T, 512, 2048);
  transpose_cast<<<dim3(16, 64), blk, 0, stream>>>(w2, w2T, 2048, 512);
  bias_pack<<<8192, blk, 0, stream>>>(adj, edge, bp);
  ln_kernel<<<4096, blk, 0, stream>>>(x, ln1g, ln1b, nx);
  gemm_bt<<<dim3(12, 32, 1), blk, 0, stream>>>(nx, qkvT, 512, 512, 512,
                                               EpiQKV{qb, kb, vb, bq, bk, bv});
  vt_kernel<<<dim3(32, 16), blk, 0, stream>>>(vb, vbT);
  attn_kernel<<<dim3(16, 16, 4), blk, 0, stream>>>(qb, kb, vbT, bp, opt, lpt);
  combine_kernel<<<4096, blk, 0, stream>>>(opt, lpt, ao);
  gemm_bt<<<dim3(4, 32, 2), blk, 0, stream>>>(ao, woT, 512, 512, 256,
                                              EpiPart{opp, 512});
  ln_fuse2<<<4096, blk, 0, stream>>>(x, opp, bo, ln2g, ln2b, x1, n2);
  gemm_bt<<<dim3(16, 32, 1), blk, 0, stream>>>(n2, w1T, 512, 512, 512,
                                               EpiGelu{b1, hb});
  gemm_bt<<<dim3(4, 32, 4), blk, 0, stream>>>(hb, w2T, 2048, 2048, 512,
                                              EpiPart{mp, 512});
  final_combine<<<2048, blk, 0, stream>>>(x1, b2, mp, out);
}

// Round 4
// 317.567 us; speedup vs baseline: 1.3291x; 1.0129x over previous
//
#include <hip/hip_runtime.h>
#include <cstdint>
#include <cstddef>

typedef __bf16 bf16x8 __attribute__((ext_vector_type(8)));
typedef float f32x4 __attribute__((ext_vector_type(4)));
typedef const __attribute__((address_space(1))) void* gas_t;
typedef __attribute__((address_space(3))) void* las_t;

#define QSCALE 0.18033688011112042f   /* 0.125 * log2(e) */
#define BSCALE 0.14426950408889634f   /* 0.1 * log2(e)   */

__device__ __forceinline__ unsigned short f2bf(float f) {
  union { float f; unsigned u; } v; v.f = f;
  unsigned r = v.u + 0x7FFFu + ((v.u >> 16) & 1u);   // RNE
  return (unsigned short)(r >> 16);
}
__device__ __forceinline__ unsigned short f2bf_fast(float f) {
  union { float f; unsigned u; } v; v.f = f;
  return (unsigned short)((v.u + 0x8000u) >> 16);    // round-nearest-away (p>=0)
}
__device__ __forceinline__ float bf2f(unsigned short h) {
  union { unsigned u; float f; } v; v.u = ((unsigned)h) << 16;
  return v.f;
}
__device__ __forceinline__ void gll16(const void* g, void* l) {
  __builtin_amdgcn_global_load_lds((gas_t)g, (las_t)l, 16, 0, 0);
}

// ---------------- weight transpose + bf16 cast:  out[C][R] = bf16(in[R][C]) ----------------
__global__ __launch_bounds__(256) void transpose_cast(const float* __restrict__ in,
                                                      unsigned short* __restrict__ out,
                                                      int R, int C) {
  __shared__ float tile[32][33];
  int bx = blockIdx.x * 32, by = blockIdx.y * 32;
  int tx = threadIdx.x & 31, tg = threadIdx.x >> 5;
  #pragma unroll
  for (int i = 0; i < 4; i++) {
    int r = tg * 4 + i;
    tile[r][tx] = in[(size_t)(by + r) * C + bx + tx];
  }
  __syncthreads();
  #pragma unroll
  for (int i = 0; i < 4; i++) {
    int r = tg * 4 + i;
    out[(size_t)(bx + r) * R + by + tx] = f2bf(tile[tx][r]);
  }
}

struct TP4 { const float* in[4]; unsigned short* out[4]; };
__global__ __launch_bounds__(256) void transpose_cast4(TP4 p) {  // 512x512 each
  __shared__ float tile[32][33];
  const float* in = p.in[blockIdx.z];
  unsigned short* out = p.out[blockIdx.z];
  int bx = blockIdx.x * 32, by = blockIdx.y * 32;
  int tx = threadIdx.x & 31, tg = threadIdx.x >> 5;
  #pragma unroll
  for (int i = 0; i < 4; i++) {
    int r = tg * 4 + i;
    tile[r][tx] = in[(size_t)(by + r) * 512 + bx + tx];
  }
  __syncthreads();
  #pragma unroll
  for (int i = 0; i < 4; i++) {
    int r = tg * 4 + i;
    out[(size_t)(bx + r) * 512 + by + tx] = f2bf(tile[tx][r]);
  }
}

// ---------------- bias pack: bf16( adj>0 ? 0.1*edge*adj*log2e - 20 : -30000 ) ----------------
__global__ __launch_bounds__(256) void bias_pack(const int* __restrict__ adj,
                                                 const float* __restrict__ edge,
                                                 unsigned short* __restrict__ bp) {
  size_t i = ((size_t)blockIdx.x * 256 + threadIdx.x) * 4;
  int4 a = *(const int4*)(adj + i);
  float4 e = *(const float4*)(edge + i);
  ushort4 r;
  r.x = a.x > 0 ? f2bf(BSCALE * e.x * (float)a.x - 20.0f) : f2bf(-30000.0f);
  r.y = a.y > 0 ? f2bf(BSCALE * e.y * (float)a.y - 20.0f) : f2bf(-30000.0f);
  r.z = a.z > 0 ? f2bf(BSCALE * e.z * (float)a.z - 20.0f) : f2bf(-30000.0f);
  r.w = a.w > 0 ? f2bf(BSCALE * e.w * (float)a.w - 20.0f) : f2bf(-30000.0f);
  *(ushort4*)(bp + i) = r;
}

// ---------------- LayerNorm over D=512 (ln1) ----------------
__global__ __launch_bounds__(256) void ln_kernel(const float* __restrict__ x,
                                                 const float* __restrict__ g,
                                                 const float* __restrict__ bt,
                                                 unsigned short* __restrict__ out) {
  int row = blockIdx.x, tid = threadIdx.x;
  float2 v = *(const float2*)(x + (size_t)row * 512 + tid * 2);
  float s = v.x + v.y, s2 = v.x * v.x + v.y * v.y;
  #pragma unroll
  for (int m = 1; m < 64; m <<= 1) { s += __shfl_xor(s, m, 64); s2 += __shfl_xor(s2, m, 64); }
  __shared__ float red[8];
  int w = tid >> 6;
  if ((tid & 63) == 0) { red[w * 2] = s; red[w * 2 + 1] = s2; }
  __syncthreads();
  float ts = red[0] + red[2] + red[4] + red[6];
  float ts2 = red[1] + red[3] + red[5] + red[7];
  float mu = ts * (1.0f / 512.0f);
  float rs = rsqrtf(ts2 * (1.0f / 512.0f) - mu * mu + 1e-5f);
  int c = tid * 2;
  ushort2 o;
  o.x = f2bf((v.x - mu) * rs * g[c] + bt[c]);
  o.y = f2bf((v.y - mu) * rs * g[c + 1] + bt[c + 1]);
  *(ushort2*)(out + (size_t)row * 512 + c) = o;
}

// ---- fused: x1 = x + bo + p0 + p1 (bf16 partials); then LN -> n2; also store x1 fp32 ----
__global__ __launch_bounds__(256) void ln_fuse2(const float* __restrict__ x,
                                                const unsigned short* __restrict__ opp,
                                                const float* __restrict__ bo,
                                                const float* __restrict__ g,
                                                const float* __restrict__ bt,
                                                float* __restrict__ x1,
                                                unsigned short* __restrict__ n2) {
  const size_t MN = (size_t)4096 * 512;
  int row = blockIdx.x, tid = threadIdx.x;
  int c = tid * 2;
  size_t idx = (size_t)row * 512 + c;
  float2 xv = *(const float2*)(x + idx);
  ushort2 p0 = *(const ushort2*)(opp + idx);
  ushort2 p1 = *(const ushort2*)(opp + MN + idx);
  float2 v;
  v.x = xv.x + bo[c]     + bf2f(p0.x) + bf2f(p1.x);
  v.y = xv.y + bo[c + 1] + bf2f(p0.y) + bf2f(p1.y);
  float s = v.x + v.y, s2 = v.x * v.x + v.y * v.y;
  #pragma unroll
  for (int m = 1; m < 64; m <<= 1) { s += __shfl_xor(s, m, 64); s2 += __shfl_xor(s2, m, 64); }
  __shared__ float red[8];
  int w = tid >> 6;
  if ((tid & 63) == 0) { red[w * 2] = s; red[w * 2 + 1] = s2; }
  __syncthreads();
  float ts = red[0] + red[2] + red[4] + red[6];
  float ts2 = red[1] + red[3] + red[5] + red[7];
  float mu = ts * (1.0f / 512.0f);
  float rs = rsqrtf(ts2 * (1.0f / 512.0f) - mu * mu + 1e-5f);
  *(float2*)(x1 + idx) = v;
  ushort2 o;
  o.x = f2bf((v.x - mu) * rs * g[c] + bt[c]);
  o.y = f2bf((v.y - mu) * rs * g[c + 1] + bt[c + 1]);
  *(ushort2*)(n2 + idx) = o;
}

// ---------------- final: out = x1 + b2 + sum of 4 bf16 partials ----------------
__global__ __launch_bounds__(256) void final_combine(const float* __restrict__ x1,
                                                     const float* __restrict__ b2,
                                                     const unsigned short* __restrict__ mp,
                                                     float* __restrict__ out) {
  const size_t MN = (size_t)4096 * 512;
  size_t i = ((size_t)blockIdx.x * 256 + threadIdx.x) * 4;
  float4 xv = *(const float4*)(x1 + i);
  float4 bv = *(const float4*)(b2 + (i & 511));
  float4 a;
  a.x = xv.x + bv.x; a.y = xv.y + bv.y; a.z = xv.z + bv.z; a.w = xv.w + bv.w;
  #pragma unroll
  for (int sp = 0; sp < 4; sp++) {
    ushort4 p = *(const ushort4*)(mp + sp * MN + i);
    a.x += bf2f(p.x); a.y += bf2f(p.y); a.z += bf2f(p.z); a.w += bf2f(p.w);
  }
  *(float4*)(out + i) = a;
}

// ---------------- generic bf16 GEMM, BK=64, double-buffered, split-K via blockIdx.z ----------------
struct EpiQKV {
  unsigned short *q, *k, *v;
  const float *bq, *bk, *bv;
  __device__ void operator()(int m, int n, float val) const {
    int b = m >> 11, s = m & 2047;
    int which = n >> 9, col = n & 511;
    int h = col >> 6, d = col & 63;
    int bh = b * 8 + h;
    if (which == 0)      q[((size_t)bh * 2048 + s) * 64 + d] = f2bf((val + bq[col]) * QSCALE);
    else if (which == 1) k[((size_t)bh * 2048 + s) * 64 + d] = f2bf(val + bk[col]);
    else                 v[((size_t)bh * 2048 + s) * 64 + d] = f2bf(val + bv[col]);
  }
};
struct EpiPart {     // bf16 partials, one chunk per split
  unsigned short* dst; int ldn;
  __device__ void operator()(int m, int n, float val) const {
    dst[(size_t)blockIdx.z * 4096 * 512 + (size_t)m * ldn + n] = f2bf(val);
  }
};
struct EpiGelu {
  const float* b1; unsigned short* h;
  __device__ void operator()(int m, int n, float val) const {
    float t = val + b1[n];
    float gl = 0.5f * t * (1.0f + erff(t * 0.70710678118654752f));
    h[(size_t)m * 2048 + n] = f2bf(gl);
  }
};

template <typename Epi>
__global__ __launch_bounds__(256, 2) void gemm_bt(const unsigned short* __restrict__ A,
                                                  const unsigned short* __restrict__ Bt,
                                                  int lda, int ldb, int kchunk, Epi epi) {
  __shared__ unsigned short a_lds[2][128 * 64];
  __shared__ unsigned short b_lds[2][128 * 64];
  const int tid = threadIdx.x;
  const int lane = tid & 63;
  const int w = tid >> 6;
  const int l15 = lane & 15, quad = lane >> 4;
  const int wm = w >> 1, wn = w & 1;
  const int m0 = blockIdx.y * 128, n0 = blockIdx.x * 128;
  const int K0 = blockIdx.z * kchunk;
  const int nIter = kchunk >> 6;

  f32x4 acc[4][4] = {};

  // stage iteration 0 into buffer 0
  #pragma unroll
  for (int i = 0; i < 4; i++) {
    int c = tid + i * 256;
    int g = c >> 6;
    int row = (g >> 1) * 16 + l15;
    int col = (g & 1) * 32 + quad * 8;
    gll16(A + (size_t)(m0 + row) * lda + K0 + col, a_lds[0] + (size_t)(c & ~63) * 8);
    gll16(Bt + (size_t)(n0 + row) * ldb + K0 + col, b_lds[0] + (size_t)(c & ~63) * 8);
  }

  for (int it = 0; it < nIter; it++) {
    const int cur = it & 1;
    __syncthreads();            // buf[cur] staged; prior reads of buf[1-cur] complete
    if (it + 1 < nIter) {
      const int kn = K0 + (it + 1) * 64;
      #pragma unroll
      for (int i = 0; i < 4; i++) {
        int c = tid + i * 256;
        int g = c >> 6;
        int row = (g >> 1) * 16 + l15;
        int col = (g & 1) * 32 + quad * 8;
        gll16(A + (size_t)(m0 + row) * lda + kn + col, a_lds[1 - cur] + (size_t)(c & ~63) * 8);
        gll16(Bt + (size_t)(n0 + row) * ldb + kn + col, b_lds[1 - cur] + (size_t)(c & ~63) * 8);
      }
    }
    bf16x8 af[4][2], bfr[4][2];
    #pragma unroll
    for (int t = 0; t < 4; t++)
      #pragma unroll
      for (int ks = 0; ks < 2; ks++) {
        af[t][ks]  = *(const bf16x8*)(a_lds[cur] + (((size_t)(wm * 4 + t) * 2 + ks) * 64 + lane) * 8);
        bfr[t][ks] = *(const bf16x8*)(b_lds[cur] + (((size_t)(wn * 4 + t) * 2 + ks) * 64 + lane) * 8);
      }
    #pragma unroll
    for (int mt = 0; mt < 4; mt++)
      #pragma unroll
      for (int nt = 0; nt < 4; nt++) {
        acc[mt][nt] = __builtin_amdgcn_mfma_f32_16x16x32_bf16(af[mt][0], bfr[nt][0], acc[mt][nt], 0, 0, 0);
        acc[mt][nt] = __builtin_amdgcn_mfma_f32_16x16x32_bf16(af[mt][1], bfr[nt][1], acc[mt][nt], 0, 0, 0);
      }
  }
  #pragma unroll
  for (int mt = 0; mt < 4; mt++)
    #pragma unroll
    for (int nt = 0; nt < 4; nt++)
      #pragma unroll
      for (int r = 0; r < 4; r++)
        epi(m0 + wm * 64 + mt * 16 + quad * 4 + r, n0 + wn * 64 + nt * 16 + l15, acc[mt][nt][r]);
}

// ---------------- V transpose: vb[bh][s][d] -> vbT[bh][d][s], 64x64 tiles ----------------
__global__ __launch_bounds__(256) void vt_kernel(const unsigned short* __restrict__ vb,
                                                 unsigned short* __restrict__ vbT) {
  __shared__ unsigned short tile[64][72];
  const int bh = blockIdx.y, s0 = blockIdx.x * 64;
  const int tid = threadIdx.x;
  const unsigned short* src = vb + ((size_t)bh * 2048 + s0) * 64;
  #pragma unroll
  for (int i = 0; i < 2; i++) {
    int r = (tid >> 3) + i * 32;
    int c8 = (tid & 7) * 8;
    *(uint4*)(&tile[r][c8]) = *(const uint4*)(src + (size_t)r * 64 + c8);
  }
  __syncthreads();
  unsigned short* dst = vbT + (size_t)bh * 64 * 2048 + s0;
  #pragma unroll
  for (int i = 0; i < 2; i++) {
    int d = (tid >> 3) + i * 32;
    int s8 = (tid & 7) * 8;
    ushort4 o0, o1;
    o0.x = tile[s8 + 0][d]; o0.y = tile[s8 + 1][d]; o0.z = tile[s8 + 2][d]; o0.w = tile[s8 + 3][d];
    o1.x = tile[s8 + 4][d]; o1.y = tile[s8 + 5][d]; o1.z = tile[s8 + 6][d]; o1.w = tile[s8 + 7][d];
    *(ushort4*)(dst + (size_t)d * 2048 + s8) = o0;
    *(ushort4*)(dst + (size_t)d * 2048 + s8 + 4) = o1;
  }
}

// ---------------- flash attention v4: double-buffered K/V, one barrier per tile ----------------
// split over 3 uneven key chunks (11/11/10 tiles), 768 blocks = 3/CU.
__global__ __launch_bounds__(256, 3) void attn_kernel(const unsigned short* __restrict__ Q,
                                                      const unsigned short* __restrict__ Kb,
                                                      const unsigned short* __restrict__ VT,
                                                      const unsigned short* __restrict__ biasp,
                                                      unsigned short* __restrict__ o_part,
                                                      float* __restrict__ l_part) {
  __shared__ unsigned short k_lds[2][64 * 64];
  __shared__ unsigned short v_lds[2][64 * 64];
  __shared__ unsigned short p_lds[4][2][16 * 68];

  const int tid = threadIdx.x;
  const int lane = tid & 63, w = tid >> 6;
  const int l15 = lane & 15, quad = lane >> 4;
  const int bh = blockIdx.x, b = bh >> 3;
  const int q0 = blockIdx.y * 128;
  const int split = blockIdx.z;

  bf16x8 qf[2][2];
  const unsigned short* brow[2];
  #pragma unroll
  for (int g = 0; g < 2; g++) {
    const unsigned short* qrow = Q + ((size_t)bh * 2048 + q0 + w * 32 + g * 16 + l15) * 64;
    qf[g][0] = *(const bf16x8*)(qrow + quad * 8);
    qf[g][1] = *(const bf16x8*)(qrow + 32 + quad * 8);
    brow[g] = biasp + ((size_t)b * 2048 + q0 + w * 32 + g * 16 + l15) * 2048;
  }

  f32x4 o_acc[2][4] = {};
  float l_acc[2] = {0.0f, 0.0f};

  const unsigned short* kbase = Kb + (size_t)bh * 2048 * 64;
  const unsigned short* vbase = VT + (size_t)bh * 64 * 2048;

  const int kt0 = split * 11;
  const int kt1 = (kt0 + 11 < 32) ? kt0 + 11 : 32;

  // stage kt0 into buffer 0; preload its bias
  #pragma unroll
  for (int i = 0; i < 2; i++) {
    int c = tid + i * 256;
    int g = c >> 6;
    int rr = (g >> 1) * 16 + l15;
    int cc = (g & 1) * 32 + quad * 8;
    gll16(kbase + (size_t)(kt0 * 64 + rr) * 64 + cc, k_lds[0] + (size_t)(c & ~63) * 8);
    gll16(vbase + (size_t)rr * 2048 + kt0 * 64 + cc, v_lds[0] + (size_t)(c & ~63) * 8);
  }
  ushort4 blc[2][4];
  #pragma unroll
  for (int g = 0; g < 2; g++)
    #pragma unroll
    for (int mt = 0; mt < 4; mt++)
      blc[g][mt] = *(const ushort4*)(brow[g] + kt0 * 64 + mt * 16 + quad * 4);

  for (int kt = kt0; kt < kt1; kt++) {
    const int cur = (kt - kt0) & 1;
    __syncthreads();            // buf[cur] staged; prior reads of buf[1-cur] complete

    const int ktn = (kt + 1 < kt1) ? kt + 1 : kt;
    #pragma unroll
    for (int i = 0; i < 2; i++) {
      int c = tid + i * 256;
      int g = c >> 6;
      int rr = (g >> 1) * 16 + l15;
      int cc = (g & 1) * 32 + quad * 8;
      gll16(kbase + (size_t)(ktn * 64 + rr) * 64 + cc, k_lds[1 - cur] + (size_t)(c & ~63) * 8);
      gll16(vbase + (size_t)rr * 2048 + ktn * 64 + cc, v_lds[1 - cur] + (size_t)(c & ~63) * 8);
    }
    ushort4 bln[2][4];
    #pragma unroll
    for (int g = 0; g < 2; g++)
      #pragma unroll
      for (int mt = 0; mt < 4; mt++)
        bln[g][mt] = *(const ushort4*)(brow[g] + ktn * 64 + mt * 16 + quad * 4);

    // scores: S^T tiles [16 keys x 16 q], bias as C input
    #pragma unroll
    for (int mt = 0; mt < 4; mt++) {
      bf16x8 a0 = *(const bf16x8*)(k_lds[cur] + ((size_t)(mt * 2 + 0) * 64 + lane) * 8);
      bf16x8 a1 = *(const bf16x8*)(k_lds[cur] + ((size_t)(mt * 2 + 1) * 64 + lane) * 8);
      #pragma unroll
      for (int g = 0; g < 2; g++) {
        f32x4 cb;
        cb[0] = bf2f(blc[g][mt].x); cb[1] = bf2f(blc[g][mt].y);
        cb[2] = bf2f(blc[g][mt].z); cb[3] = bf2f(blc[g][mt].w);
        f32x4 accv = __builtin_amdgcn_mfma_f32_16x16x32_bf16(a0, qf[g][0], cb, 0, 0, 0);
        accv = __builtin_amdgcn_mfma_f32_16x16x32_bf16(a1, qf[g][1], accv, 0, 0, 0);
        float p0 = exp2f(accv[0]), p1 = exp2f(accv[1]);
        float p2 = exp2f(accv[2]), p3 = exp2f(accv[3]);
        l_acc[g] += (p0 + p1) + (p2 + p3);
        ushort4 pv;
        pv.x = f2bf_fast(p0); pv.y = f2bf_fast(p1); pv.z = f2bf_fast(p2); pv.w = f2bf_fast(p3);
        *(ushort4*)(p_lds[w][g] + l15 * 68 + mt * 16 + quad * 4) = pv;
      }
    }

    bf16x8 pf[2][2];
    #pragma unroll
    for (int g = 0; g < 2; g++) {
      pf[g][0] = *(const bf16x8*)(p_lds[w][g] + l15 * 68 + quad * 8);
      pf[g][1] = *(const bf16x8*)(p_lds[w][g] + l15 * 68 + 32 + quad * 8);
    }
    #pragma unroll
    for (int dt = 0; dt < 4; dt++) {
      bf16x8 v0 = *(const bf16x8*)(v_lds[cur] + ((size_t)(dt * 2 + 0) * 64 + lane) * 8);
      bf16x8 v1 = *(const bf16x8*)(v_lds[cur] + ((size_t)(dt * 2 + 1) * 64 + lane) * 8);
      #pragma unroll
      for (int g = 0; g < 2; g++) {
        o_acc[g][dt] = __builtin_amdgcn_mfma_f32_16x16x32_bf16(pf[g][0], v0, o_acc[g][dt], 0, 0, 0);
        o_acc[g][dt] = __builtin_amdgcn_mfma_f32_16x16x32_bf16(pf[g][1], v1, o_acc[g][dt], 0, 0, 0);
      }
    }

    #pragma unroll
    for (int g = 0; g < 2; g++)
      #pragma unroll
      for (int mt = 0; mt < 4; mt++)
        blc[g][mt] = bln[g][mt];
  }

  const size_t obase = ((size_t)split * 16 + bh) * 2048;
  #pragma unroll
  for (int g = 0; g < 2; g++) {
    float l = l_acc[g];
    l += __shfl_xor(l, 16, 64);
    l += __shfl_xor(l, 32, 64);
    if (quad == 0) l_part[obase + q0 + w * 32 + g * 16 + l15] = l;
    #pragma unroll
    for (int dt = 0; dt < 4; dt++)
      #pragma unroll
      for (int r = 0; r < 4; r++)
        o_part[(obase + q0 + w * 32 + g * 16 + quad * 4 + r) * 64 + dt * 16 + l15] =
            f2bf(o_acc[g][dt][r]);
  }
}

// ---------------- combine: ao = bf16( sum_sp O_sp / sum_sp l_sp ) ----------------
__global__ __launch_bounds__(256) void combine_kernel(const unsigned short* __restrict__ o_part,
                                                      const float* __restrict__ l_part,
                                                      unsigned short* __restrict__ ao) {
  const int row = blockIdx.x;           // b*2048 + s
  const int b = row >> 11, s = row & 2047;
  const int col = threadIdx.x * 2;
  const int h = col >> 6, d = col & 63;
  const int bh = b * 8 + h;
  float ox = 0.0f, oy = 0.0f, l = 0.0f;
  #pragma unroll
  for (int sp = 0; sp < 3; sp++) {
    size_t base = (size_t)(sp * 16 + bh) * 2048 + s;
    ushort2 o = *(const ushort2*)(o_part + base * 64 + d);
    ox += bf2f(o.x); oy += bf2f(o.y);
    l += l_part[base];
  }
  float inv = 1.0f / l;
  ushort2 o;
  o.x = f2bf(ox * inv);
  o.y = f2bf(oy * inv);
  *(ushort2*)(ao + (size_t)row * 512 + col) = o;
}

// ---------------- host launch ----------------
extern "C" void kernel_launch(void* const* d_in, const int* in_sizes, int n_in,
                              void* d_out, int out_size, void* d_ws, size_t ws_size,
                              hipStream_t stream) {
  (void)in_sizes; (void)n_in; (void)out_size; (void)ws_size;
  const float* x    = (const float*)d_in[0];
  const int*   adj  = (const int*)d_in[1];
  const float* edge = (const float*)d_in[2];
  const float* ln1g = (const float*)d_in[3];
  const float* ln1b = (const float*)d_in[4];
  const float* ln2g = (const float*)d_in[5];
  const float* ln2b = (const float*)d_in[6];
  const float* wq = (const float*)d_in[7];  const float* bq = (const float*)d_in[8];
  const float* wk = (const float*)d_in[9];  const float* bk = (const float*)d_in[10];
  const float* wv = (const float*)d_in[11]; const float* bv = (const float*)d_in[12];
  const float* wo = (const float*)d_in[13]; const float* bo = (const float*)d_in[14];
  const float* w1 = (const float*)d_in[15]; const float* b1 = (const float*)d_in[16];
  const float* w2 = (const float*)d_in[17]; const float* b2 = (const float*)d_in[18];
  float* out = (float*)d_out;

  // --- workspace layout (aliased; temporally disjoint uses) -----------------
  char* ws = (char*)d_ws;
  unsigned short* qkvT = (unsigned short*)ws; ws += (size_t)1536 * 512 * 2;
  unsigned short* woT  = (unsigned short*)ws; ws += (size_t)512 * 512 * 2;
  unsigned short* w1T  = (unsigned short*)ws; ws += (size_t)2048 * 512 * 2;
  unsigned short* w2T  = (unsigned short*)ws; ws += (size_t)512 * 2048 * 2;
  // bp (bf16 2*2048*2048, dead after attn)  ||  opp (bf16 2 outproj partials)
  unsigned short* bp   = (unsigned short*)ws;
  unsigned short* opp  = (unsigned short*)ws; ws += (size_t)2 * 2048 * 2048 * 2;
  // nx (dead after QKV gemm) || n2
  unsigned short* nx   = (unsigned short*)ws;
  unsigned short* n2   = (unsigned short*)ws; ws += (size_t)4096 * 512 * 2;
  // qb (dead after attn) || ao
  unsigned short* qb   = (unsigned short*)ws;
  unsigned short* ao   = (unsigned short*)ws; ws += (size_t)4096 * 512 * 2;
  unsigned short* kb   = (unsigned short*)ws; ws += (size_t)4096 * 512 * 2;
  // vb+vbT (dead after attn) || x1 (fp32)
  unsigned short* vb   = (unsigned short*)ws;
  float*          x1   = (float*)ws;          ws += (size_t)4096 * 512 * 2;
  unsigned short* vbT  = (unsigned short*)ws; ws += (size_t)4096 * 512 * 2;
  // region1: [opt bf16 12.6MB | lpt 0.4MB] (dead after combine) || [hb 16.78MB | mp 16.78MB]
  char* region1 = ws;
  unsigned short* opt  = (unsigned short*)region1;
  unsigned short* hb   = (unsigned short*)region1;
  float*          lpt  = (float*)(region1 + (size_t)3 * 16 * 2048 * 64 * 2);
  unsigned short* mp   = (unsigned short*)(region1 + (size_t)16777216);

  dim3 blk(256);
  TP4 tp; tp.in[0] = wq; tp.in[1] = wk; tp.in[2] = wv; tp.in[3] = wo;
  tp.out[0] = qkvT; tp.out[1] = qkvT + (size_t)512 * 512;
  tp.out[2] = qkvT + (size_t)2 * 512 * 512; tp.out[3] = woT;
  transpose_cast4<<<dim3(16, 16, 4), blk, 0, stream>>>(tp);
  transpose_cast<<<dim3(64, 16), blk, 0, stream>>>(w1, w1T, 512, 2048);
  transpose_cast<<<dim3(16, 64), blk, 0, stream>>>(w2, w2T, 2048, 512);
  bias_pack<<<8192, blk, 0, stream>>>(adj, edge, bp);
  ln_kernel<<<4096, blk, 0, stream>>>(x, ln1g, ln1b, nx);
  gemm_bt<<<dim3(12, 32, 1), blk, 0, stream>>>(nx, qkvT, 512, 512, 512,
                                               EpiQKV{qb, kb, vb, bq, bk, bv});
  vt_kernel<<<dim3(32, 16), blk, 0, stream>>>(vb, vbT);
  attn_kernel<<<dim3(16, 16, 3), blk, 0, stream>>>(qb, kb, vbT, bp, opt, lpt);
  combine_kernel<<<4096, blk, 0, stream>>>(opt, lpt, ao);
  gemm_bt<<<dim3(4, 32, 2), blk, 0, stream>>>(ao, woT, 512, 512, 256,
                                              EpiPart{opp, 512});
  ln_fuse2<<<4096, blk, 0, stream>>>(x, opp, bo, ln2g, ln2b, x1, n2);
  gemm_bt<<<dim3(16, 32, 1), blk, 0, stream>>>(n2, w1T, 512, 512, 512,
                                               EpiGelu{b1, hb});
  gemm_bt<<<dim3(4, 32, 4), blk, 0, stream>>>(hb, w2T, 2048, 2048, 512,
                                              EpiPart{mp, 512});
  final_combine<<<2048, blk, 0, stream>>>(x1, b2, mp, out);
}